// Round 11
// baseline (197.793 us; speedup 1.0000x reference)
//
#include <hip/hip_runtime.h>
#include <hip/hip_fp16.h>
#include <math.h>

#define NSLOTS 4096
#define DIM    128
#define HDIM   1024
#define NTOK   16384   // 4 * 4096
#define SCALE  0.08838834764831845f  // 1/sqrt(128)
#define REPS   1e-10f

typedef __attribute__((ext_vector_type(8))) short bf16x8;
typedef __attribute__((ext_vector_type(4))) float f32x4;

// ---- packed (score | 4095-slot) helpers -----------------------------------
// Low 12 mantissa bits replaced by (4095-slot): float compare = score desc,
// then slot asc. fp32 rescue re-ranks the 16-candidate pool exactly, so only
// pool membership matters. Top-8-per-lane guarantees the true bf16-top-8 is
// always in the pool (≤7 elements outrank it anywhere).
__device__ __forceinline__ float pack_score(float biased, unsigned inv_idx) {
    return __uint_as_float((__float_as_uint(biased) & 0xFFFFF000u) | inv_idx);
}
#define PACK_NEG_INF __uint_as_float(0xFF7FF000u)   // ~ -FLT_MAX, valid finite

// Branchless insert into ascending sorted r[0..7] (r[7]=max), drop min.
__device__ __forceinline__ void ins_packed(float (&r)[8], float x) {
    #pragma unroll
    for (int i = 0; i < 7; ++i) r[i] = __builtin_amdgcn_fmed3f(r[i], x, r[i + 1]);
    r[7] = fmaxf(r[7], x);
}

// Pop-merge 4 kseg-lanes' sorted top-8 (32 values) -> sorted top-16 (desc,
// packed) into LDS. Group = lanes {l, l^16, l^32, l^48}.
__device__ __forceinline__ void merge_out16(float (&r)[8], int kseg, float* outS) {
    float hv = r[7];
    #pragma unroll
    for (int rnd = 0; rnd < 16; ++rnd) {
        float bv = hv;
        bv = fmaxf(bv, __shfl_xor(bv, 16, 64));
        bv = fmaxf(bv, __shfl_xor(bv, 32, 64));
        if ((rnd >> 2) == kseg) outS[rnd] = bv;   // each kseg-lane writes 4
        if (hv == bv) {   // my head won (packed values distinct in group): pop
            #pragma unroll
            for (int m2 = 7; m2 > 0; --m2) r[m2] = r[m2 - 1];
            r[0] = PACK_NEG_INF;
            hv = r[7];
        }
    }
}

// ---------------- kernel 0: prep (bf16 q/k + fp16 V + log-rel) --------------
__device__ __forceinline__ ushort f2bf(float f) {   // RNE
    unsigned u = __float_as_uint(f);
    return (ushort)((u + 0x7fffu + ((u >> 16) & 1u)) >> 16);
}
// kbp chunk C (16 B = 8 bf16): C = t16*256 + kc*64 + l
//   t16 = 16-slot tile (0..255), kc = K-chunk (0..3), l = lane
//   source = keys[slot = t16*16 + (l&15)][kc*32 + (l>>4)*8 .. +8)
#define QB_N  524288   // q bf16 convert, float4 granules
#define KBP_N 65536    // k permuted bf16 chunks
#define LR_N  4096     // log-reliability
#define VH_N  524288   // V fp16 convert, 8 floats per thread
__global__ void prep_kernel(const float* __restrict__ q, const float* __restrict__ k,
                            const float* __restrict__ rel, const float* __restrict__ v,
                            ushort* __restrict__ qb, ushort* __restrict__ kbp,
                            float* __restrict__ lr, ushort* __restrict__ vh) {
    int gid = blockIdx.x * 256 + threadIdx.x;
    if (gid < QB_N) {                         // qb row-major: 2,097,152 floats / 4
        float4 vv = ((const float4*)q)[gid];
        ushort4 o; o.x = f2bf(vv.x); o.y = f2bf(vv.y); o.z = f2bf(vv.z); o.w = f2bf(vv.w);
        ((ushort4*)qb)[gid] = o;
    } else if (gid < QB_N + KBP_N) {          // kbp fragment-permuted chunks
        int C = gid - QB_N;
        int l = C & 63, kc = (C >> 6) & 3, t16 = C >> 8;
        int slot = t16 * 16 + (l & 15);
        int doff = kc * 32 + (l >> 4) * 8;
        const float4* src = (const float4*)(k + (size_t)slot * DIM + doff);
        float4 v0 = src[0], v1 = src[1];
        union { ushort u[8]; uint4 v; } o;
        o.u[0] = f2bf(v0.x); o.u[1] = f2bf(v0.y); o.u[2] = f2bf(v0.z); o.u[3] = f2bf(v0.w);
        o.u[4] = f2bf(v1.x); o.u[5] = f2bf(v1.y); o.u[6] = f2bf(v1.z); o.u[7] = f2bf(v1.w);
        ((uint4*)kbp)[C] = o.v;
    } else if (gid < QB_N + KBP_N + LR_N) {
        int g = gid - QB_N - KBP_N;
        lr[g] = logf(rel[g] + REPS);
    } else if (gid < QB_N + KBP_N + LR_N + VH_N) {   // V fp32 -> fp16 (RNE)
        int g = gid - QB_N - KBP_N - LR_N;
        const float4* src = (const float4*)v + (size_t)g * 2;
        float4 a = src[0], b = src[1];
        union { _Float16 h[8]; uint4 u; } o;
        o.h[0] = (_Float16)a.x; o.h[1] = (_Float16)a.y;
        o.h[2] = (_Float16)a.z; o.h[3] = (_Float16)a.w;
        o.h[4] = (_Float16)b.x; o.h[5] = (_Float16)b.y;
        o.h[6] = (_Float16)b.z; o.h[7] = (_Float16)b.w;
        ((uint4*)vh)[g] = o.u;
    }
}

// ---------------- kernel 1: MFMA router + packed top-8 ----------------------
// Grid 1024 x 512 thr (8 waves): block = (token-group of 32, slot-HALF).
// Loop body = r7's proven 52-VGPR structure (K tiles in registers from L2,
// no LDS staging, no in-loop barriers, explicit prefetch; each tile feeds TWO
// 16-token MFMA column blocks). r9's slot-halved grid gives 4 blocks/CU x 8
// waves = 32 waves/CU = 8 waves/EU — but compiled with launch_bounds(512,4):
// the 2nd arg is a regalloc MINIMUM, not a runtime cap; at 52 VGPR (<=64
// granule) HW residency reaches 8 waves/EU from the grid alone. r8/r9's
// spills came from requesting 8 in launch_bounds (forces <=64-arch split).
// Wave = 256 slots (16 tiles); per-lane partition 64 slots, top-8/lane;
// 4-lane merge -> per-256-slot top-16; 8-way merge -> EXACT half top-16,
// PACKED to cpool[token][half*16..]. Rescue pre-merges the two halves.
__launch_bounds__(512, 4)
__global__ void route_kernel(const ushort* __restrict__ qb,
                             const ushort* __restrict__ kbp,
                             const float*  __restrict__ lr,
                             float* __restrict__ cpool) {
    __shared__ float qS[32][8][17];   // [token][wave-list][16 +1 pad] = 17 KB
    const int tid  = threadIdx.x;
    const int lane = tid & 63;
    const int w    = tid >> 6;     // wave 0..7 (256-slot range within half)
    const int m    = lane & 15;    // token col
    const int kseg = lane >> 4;
    const int tg   = blockIdx.x >> 1;
    const int half = blockIdx.x & 1;
    const int tokbase = tg * 32;

    // stationary B-frags (queries) for both 16-token halves
    bf16x8 bF0[4], bF1[4];
    const ushort* q0 = qb + (size_t)(tokbase + m) * DIM + kseg * 8;
    const ushort* q1 = qb + (size_t)(tokbase + 16 + m) * DIM + kseg * 8;
    #pragma unroll
    for (int kc = 0; kc < 4; ++kc) {
        bF0[kc] = *(const bf16x8*)(q0 + kc * 32);
        bF1[kc] = *(const bf16x8*)(q1 + kc * 32);
    }

    float R0[8], R1[8];
    #pragma unroll
    for (int i = 0; i < 8; ++i) { R0[i] = PACK_NEG_INF; R1[i] = PACK_NEG_INF; }

    const uint4* kb4 = (const uint4*)kbp;
    const int tbase = half * 128 + w * 16;   // this wave's first 16-slot tile

    uint4 A[4], N[4];
    #pragma unroll
    for (int kc = 0; kc < 4; ++kc)
        A[kc] = kb4[(size_t)tbase * 256 + kc * 64 + lane];

    for (int t = 0; t < 16; ++t) {
        if (t < 15) {
            #pragma unroll
            for (int kc = 0; kc < 4; ++kc)
                N[kc] = kb4[(size_t)(tbase + t + 1) * 256 + kc * 64 + lane];
        }
        f32x4 acc0 = {0.f, 0.f, 0.f, 0.f};
        f32x4 acc1 = {0.f, 0.f, 0.f, 0.f};
        #pragma unroll
        for (int kc = 0; kc < 4; ++kc) {
            bf16x8 aF = *(const bf16x8*)&A[kc];
            acc0 = __builtin_amdgcn_mfma_f32_16x16x32_bf16(aF, bF0[kc], acc0, 0, 0, 0);
            acc1 = __builtin_amdgcn_mfma_f32_16x16x32_bf16(aF, bF1[kc], acc1, 0, 0, 0);
        }
        const int base = half * 2048 + w * 256 + t * 16;
        float4 lrv = ((const float4*)lr)[(base >> 2) + kseg];
        unsigned invb = 4095u - (unsigned)(base + kseg * 4);
        ins_packed(R0, pack_score(acc0[0] + lrv.x, invb));
        ins_packed(R0, pack_score(acc0[1] + lrv.y, invb - 1));
        ins_packed(R0, pack_score(acc0[2] + lrv.z, invb - 2));
        ins_packed(R0, pack_score(acc0[3] + lrv.w, invb - 3));
        ins_packed(R1, pack_score(acc1[0] + lrv.x, invb));
        ins_packed(R1, pack_score(acc1[1] + lrv.y, invb - 1));
        ins_packed(R1, pack_score(acc1[2] + lrv.z, invb - 2));
        ins_packed(R1, pack_score(acc1[3] + lrv.w, invb - 3));
        #pragma unroll
        for (int kc = 0; kc < 4; ++kc) A[kc] = N[kc];
    }

    merge_out16(R0, kseg, &qS[m][w][0]);
    merge_out16(R1, kseg, &qS[m + 16][w][0]);
    __syncthreads();

    // 8-way merge of the sorted-desc range lists -> exact HALF top-16, packed
    if (tid < 32) {
        const int token = tokbase + tid;
        int p[8] = {0, 0, 0, 0, 0, 0, 0, 0};
        #pragma unroll
        for (int c = 0; c < 16; ++c) {
            float bv = -INFINITY; int bq = 0;
            #pragma unroll
            for (int j = 0; j < 8; ++j) {
                float v = (p[j] < 16) ? qS[tid][j][p[j]] : -INFINITY;
                if (v > bv) { bv = v; bq = j; }
            }
            cpool[(size_t)token * 32 + half * 16 + c] = bv;
            ++p[bq];
        }
    }
}

// ---------------- kernel 2: fused fp32 rescue + softmax + V gather ----------
// (r3 proven body: 59.4 us) 1 wave per token (4/block). NEW prologue (r9-
// verified): 32-wide bitonic pre-sort of the two halves' PACKED top-16 lists
// (1 float/lane, lanes 32-63 mirror) -> top-16 of the union = EXACT global
// packed top-16 = bit-identical cand. Then r3 verbatim: lane = cand(16) x
// dim-quarter(4), exact fp32 q.k, 16-wide bitonic (s desc, idx asc), softmax
// on raw scores, fused gather of 8 weighted fp16 V rows. Plain loads/stores
// (r10's NT hints measured net-negative: WRITE 66->77 MB, +2 us).
__device__ __forceinline__ float2 h2f2(unsigned u) {
    return __half22float2(*reinterpret_cast<const __half2*>(&u));
}
__launch_bounds__(256)
__global__ void rescue_gather_kernel(const float* __restrict__ query,
                                     const float* __restrict__ keys,
                                     const float* __restrict__ lr,
                                     const float* __restrict__ cpool,
                                     const ushort* __restrict__ vh,
                                     float* __restrict__ out,
                                     float* __restrict__ wout) {
    const int tid  = threadIdx.x;
    const int w    = tid >> 6;
    const int lane = tid & 63;
    const int token = blockIdx.x * 4 + w;
    const int c5 = lane & 31;

    // ---- packed pre-sort: 32 pool entries (2 disjoint halves x 16) --------
    float pv = cpool[(size_t)token * 32 + c5];
    #pragma unroll
    for (int k = 2; k <= 32; k <<= 1) {
        #pragma unroll
        for (int j = k >> 1; j >= 1; j >>= 1) {
            float p2 = __shfl_xor(pv, j, 64);
            bool mineFirst = pv > p2;     // packed: score desc, slot asc; distinct
            bool lower = (c5 & j) == 0;
            bool asc   = (c5 & k) == 0;
            bool keep  = (lower == asc) ? mineFirst : !mineFirst;
            if (!keep) pv = p2;
        }
    }
    // rank r at lane r (0..31, mirrored); this lane takes cand rank lane>>2
    float pc = __shfl(pv, lane >> 2, 64);
    int ci = 4095 - (int)(__float_as_uint(pc) & 0xFFFu);

    const int c  = lane >> 2;    // candidate 0..15
    const int qp = lane & 3;     // dim quarter (32 floats)
    const float4* q4 = (const float4*)(query + (size_t)token * DIM) + qp * 8;
    const float4* k4 = (const float4*)(keys  + (size_t)ci    * DIM) + qp * 8;
    float sum = 0.f;
    #pragma unroll
    for (int i = 0; i < 8; ++i) {
        float4 a = q4[i], b = k4[i];
        sum = fmaf(a.x, b.x, sum); sum = fmaf(a.y, b.y, sum);
        sum = fmaf(a.z, b.z, sum); sum = fmaf(a.w, b.w, sum);
    }
    sum += __shfl_xor(sum, 1, 4);
    sum += __shfl_xor(sum, 2, 4);    // all 4 twins hold the full dot
    float raw = sum;
    float s   = sum + lr[ci];        // biased, exact fp32

    // bitonic sort of 16 candidates across lanes (twins mirror; partner lane
    // = lane ^ (j*4)). "mineFirst" = ranks before = (s desc, idx asc).
    #pragma unroll
    for (int k = 2; k <= 16; k <<= 1) {
        #pragma unroll
        for (int j = k >> 1; j >= 1; j >>= 1) {
            int off = j << 2;
            float s2 = __shfl_xor(s,   off, 64);
            float r2 = __shfl_xor(raw, off, 64);
            int   i2 = __shfl_xor(ci,  off, 64);
            bool mineFirst = (s > s2) || (s == s2 && ci < i2);
            bool lower = (c & j) == 0;
            bool asc   = (c & k) == 0;
            bool keep  = (lower == asc) ? mineFirst : !mineFirst;
            if (!keep) { s = s2; raw = r2; ci = i2; }
        }
    }
    // position c now holds rank c; broadcast top-8 (raw, idx) to all lanes
    float rsel[8]; int isel[8];
    #pragma unroll
    for (int r = 0; r < 8; ++r) {
        rsel[r] = __shfl(raw, r * 4, 64);
        isel[r] = __shfl(ci,  r * 4, 64);
    }

    // softmax on raw*SCALE — computed redundantly in every lane (weights
    // needed in registers for the gather)
    float mx = -INFINITY;
    #pragma unroll
    for (int k = 0; k < 8; ++k) { rsel[k] *= SCALE; mx = fmaxf(mx, rsel[k]); }
    float e[8]; float ssum = 0.f;
    #pragma unroll
    for (int k = 0; k < 8; ++k) { e[k] = expf(rsel[k] - mx); ssum += e[k]; }
    float inv = 1.0f / ssum;
    float wk[8];
    #pragma unroll
    for (int k = 0; k < 8; ++k) wk[k] = e[k] * inv;

    if (lane == 0) {
        #pragma unroll
        for (int k = 0; k < 8; ++k) wout[(size_t)token * 8 + k] = wk[k];
    }

    // fused gather: fp16 rows, 1024 halfs = 128 uint4; lane owns
    // dims [lane*8, lane*8+8) and [512+lane*8, 512+lane*8+8)
    float oA[8], oB[8];
    #pragma unroll
    for (int i = 0; i < 8; ++i) { oA[i] = 0.f; oB[i] = 0.f; }
    #pragma unroll
    for (int k = 0; k < 8; ++k) {
        const uint4* vr = (const uint4*)vh + (size_t)isel[k] * 128;
        float wkk = wk[k];
        uint4 va = vr[lane];
        uint4 vb = vr[lane + 64];
        float2 f;
        f = h2f2(va.x); oA[0] = fmaf(wkk, f.x, oA[0]); oA[1] = fmaf(wkk, f.y, oA[1]);
        f = h2f2(va.y); oA[2] = fmaf(wkk, f.x, oA[2]); oA[3] = fmaf(wkk, f.y, oA[3]);
        f = h2f2(va.z); oA[4] = fmaf(wkk, f.x, oA[4]); oA[5] = fmaf(wkk, f.y, oA[5]);
        f = h2f2(va.w); oA[6] = fmaf(wkk, f.x, oA[6]); oA[7] = fmaf(wkk, f.y, oA[7]);
        f = h2f2(vb.x); oB[0] = fmaf(wkk, f.x, oB[0]); oB[1] = fmaf(wkk, f.y, oB[1]);
        f = h2f2(vb.y); oB[2] = fmaf(wkk, f.x, oB[2]); oB[3] = fmaf(wkk, f.y, oB[3]);
        f = h2f2(vb.z); oB[4] = fmaf(wkk, f.x, oB[4]); oB[5] = fmaf(wkk, f.y, oB[5]);
        f = h2f2(vb.w); oB[6] = fmaf(wkk, f.x, oB[6]); oB[7] = fmaf(wkk, f.y, oB[7]);
    }
    float4* orow = (float4*)(out + (size_t)token * HDIM);
    orow[lane * 2]           = make_float4(oA[0], oA[1], oA[2], oA[3]);
    orow[lane * 2 + 1]       = make_float4(oA[4], oA[5], oA[6], oA[7]);
    orow[128 + lane * 2]     = make_float4(oB[0], oB[1], oB[2], oB[3]);
    orow[128 + lane * 2 + 1] = make_float4(oB[4], oB[5], oB[6], oB[7]);
}

// ---------------- launch ----------------
extern "C" void kernel_launch(void* const* d_in, const int* in_sizes, int n_in,
                              void* d_out, int out_size, void* d_ws, size_t ws_size,
                              hipStream_t stream) {
    const float* query  = (const float*)d_in[0];
    const float* keys   = (const float*)d_in[1];
    const float* values = (const float*)d_in[2];
    const float* rel    = (const float*)d_in[3];

    float* out  = (float*)d_out;                 // [16384, 1024]
    float* wout = out + (size_t)NTOK * HDIM;     // [16384, 8]

    char* ws = (char*)d_ws;
    float*  lr    = (float*)ws;   ws += 4096 * 4;                    // 16 KB
    ushort* qb    = (ushort*)ws;  ws += (size_t)NTOK * DIM * 2;      // 4 MB
    ushort* kbp   = (ushort*)ws;  ws += (size_t)NSLOTS * DIM * 2;    // 1 MB
    float*  cpool = (float*)ws;   ws += (size_t)NTOK * 32 * 4;       // 2 MB
    ushort* vh    = (ushort*)ws;                                     // 8 MB fp16 V

    int prep_grid = (QB_N + KBP_N + LR_N + VH_N) / 256;   // = 4368
    hipLaunchKernelGGL(prep_kernel, dim3(prep_grid), dim3(256), 0, stream,
                       query, keys, rel, values, qb, kbp, lr, vh);
    hipLaunchKernelGGL(route_kernel, dim3(NTOK / 32 * 2), dim3(512), 0, stream,
                       qb, kbp, lr, cpool);
    hipLaunchKernelGGL(rescue_gather_kernel, dim3(NTOK / 4), dim3(256), 0, stream,
                       query, keys, lr, cpool, vh, out, wout);
}

// Round 12
// 187.691 us; speedup vs baseline: 1.0538x; 1.0538x over previous
//
#include <hip/hip_runtime.h>
#include <hip/hip_fp16.h>
#include <math.h>

#define NSLOTS 4096
#define DIM    128
#define HDIM   1024
#define NTOK   16384   // 4 * 4096
#define SCALE  0.08838834764831845f  // 1/sqrt(128)
#define REPS   1e-10f

typedef __attribute__((ext_vector_type(8))) short bf16x8;
typedef __attribute__((ext_vector_type(4))) float f32x4;

// ---- packed (score | 4095-slot) helpers -----------------------------------
// Low 12 mantissa bits replaced by (4095-slot): float compare = score desc,
// then slot asc. fp32 rescue re-ranks the 16-candidate pool exactly, so only
// pool membership matters. Top-8-per-lane guarantees the true bf16-top-8 is
// always in the pool (≤7 elements outrank it anywhere).
__device__ __forceinline__ float pack_score(float biased, unsigned inv_idx) {
    return __uint_as_float((__float_as_uint(biased) & 0xFFFFF000u) | inv_idx);
}
#define PACK_NEG_INF __uint_as_float(0xFF7FF000u)   // ~ -FLT_MAX, valid finite

// Branchless insert into ascending sorted r[0..7] (r[7]=max), drop min.
__device__ __forceinline__ void ins_packed(float (&r)[8], float x) {
    #pragma unroll
    for (int i = 0; i < 7; ++i) r[i] = __builtin_amdgcn_fmed3f(r[i], x, r[i + 1]);
    r[7] = fmaxf(r[7], x);
}

// Pop-merge 4 kseg-lanes' sorted top-8 (32 values) -> sorted top-16 (desc,
// packed) into LDS. Group = lanes {l, l^16, l^32, l^48}.
__device__ __forceinline__ void merge_out16(float (&r)[8], int kseg, float* outS) {
    float hv = r[7];
    #pragma unroll
    for (int rnd = 0; rnd < 16; ++rnd) {
        float bv = hv;
        bv = fmaxf(bv, __shfl_xor(bv, 16, 64));
        bv = fmaxf(bv, __shfl_xor(bv, 32, 64));
        if ((rnd >> 2) == kseg) outS[rnd] = bv;   // each kseg-lane writes 4
        if (hv == bv) {   // my head won (packed values distinct in group): pop
            #pragma unroll
            for (int m2 = 7; m2 > 0; --m2) r[m2] = r[m2 - 1];
            r[0] = PACK_NEG_INF;
            hv = r[7];
        }
    }
}

// ---------------- kernel 0: prep (bf16 q/k + fp16 V + log-rel) --------------
__device__ __forceinline__ ushort f2bf(float f) {   // RNE
    unsigned u = __float_as_uint(f);
    return (ushort)((u + 0x7fffu + ((u >> 16) & 1u)) >> 16);
}
// kbp chunk C (16 B = 8 bf16): C = t16*256 + kc*64 + l
//   t16 = 16-slot tile (0..255), kc = K-chunk (0..3), l = lane
//   source = keys[slot = t16*16 + (l&15)][kc*32 + (l>>4)*8 .. +8)
#define QB_N  524288   // q bf16 convert, float4 granules
#define KBP_N 65536    // k permuted bf16 chunks
#define LR_N  4096     // log-reliability
#define VH_N  524288   // V fp16 convert, 8 floats per thread
__global__ void prep_kernel(const float* __restrict__ q, const float* __restrict__ k,
                            const float* __restrict__ rel, const float* __restrict__ v,
                            ushort* __restrict__ qb, ushort* __restrict__ kbp,
                            float* __restrict__ lr, ushort* __restrict__ vh) {
    int gid = blockIdx.x * 256 + threadIdx.x;
    if (gid < QB_N) {                         // qb row-major: 2,097,152 floats / 4
        float4 vv = ((const float4*)q)[gid];
        ushort4 o; o.x = f2bf(vv.x); o.y = f2bf(vv.y); o.z = f2bf(vv.z); o.w = f2bf(vv.w);
        ((ushort4*)qb)[gid] = o;
    } else if (gid < QB_N + KBP_N) {          // kbp fragment-permuted chunks
        int C = gid - QB_N;
        int l = C & 63, kc = (C >> 6) & 3, t16 = C >> 8;
        int slot = t16 * 16 + (l & 15);
        int doff = kc * 32 + (l >> 4) * 8;
        const float4* src = (const float4*)(k + (size_t)slot * DIM + doff);
        float4 v0 = src[0], v1 = src[1];
        union { ushort u[8]; uint4 v; } o;
        o.u[0] = f2bf(v0.x); o.u[1] = f2bf(v0.y); o.u[2] = f2bf(v0.z); o.u[3] = f2bf(v0.w);
        o.u[4] = f2bf(v1.x); o.u[5] = f2bf(v1.y); o.u[6] = f2bf(v1.z); o.u[7] = f2bf(v1.w);
        ((uint4*)kbp)[C] = o.v;
    } else if (gid < QB_N + KBP_N + LR_N) {
        int g = gid - QB_N - KBP_N;
        lr[g] = logf(rel[g] + REPS);
    } else if (gid < QB_N + KBP_N + LR_N + VH_N) {   // V fp32 -> fp16 (RNE)
        int g = gid - QB_N - KBP_N - LR_N;
        const float4* src = (const float4*)v + (size_t)g * 2;
        float4 a = src[0], b = src[1];
        union { _Float16 h[8]; uint4 u; } o;
        o.h[0] = (_Float16)a.x; o.h[1] = (_Float16)a.y;
        o.h[2] = (_Float16)a.z; o.h[3] = (_Float16)a.w;
        o.h[4] = (_Float16)b.x; o.h[5] = (_Float16)b.y;
        o.h[6] = (_Float16)b.z; o.h[7] = (_Float16)b.w;
        ((uint4*)vh)[g] = o.u;
    }
}

// ---------------- kernel 1: MFMA router + packed top-8 ----------------------
// (r3/r7 proven: 51.9 us measured, 52 VGPR, no spills) Grid 512 x 512 thr
// (8 waves). Block = 32 tokens, all 4096 slots; wave w = slot eighth (512
// slots = 32 tiles of 16), K tiles in REGISTERS loaded from L2 (kbp 1 MB,
// L2-resident) — no LDS staging, no in-loop barriers, explicit next-tile
// prefetch. Each tile feeds TWO 16-token MFMA column blocks. Per-lane top-8
// over its 128-slot partition; 4-lane merge -> eighth top-16; 8-way merge ->
// global top-16 pool -> cand.
// CLOSED PATHS (do not revisit): >=8 waves/EU via launch_bounds -> RF split +
// spill (r8/r9: VGPR 32, scratch traffic, 2x slower); slot-halved grid at
// (512,4) -> per-wave efficiency loss cancels residency gain (r11).
__launch_bounds__(512, 4)
__global__ void route_kernel(const ushort* __restrict__ qb,
                             const ushort* __restrict__ kbp,
                             const float*  __restrict__ lr,
                             int* __restrict__ cand) {
    __shared__ float qS[32][8][17];   // [token][eighth][16 +1 pad] = 17 KB
    const int tid  = threadIdx.x;
    const int lane = tid & 63;
    const int w    = tid >> 6;     // wave = slot eighth 0..7
    const int m    = lane & 15;    // token col
    const int kseg = lane >> 4;
    const int tokbase = blockIdx.x * 32;

    // stationary B-frags (queries) for both 16-token halves
    bf16x8 bF0[4], bF1[4];
    const ushort* q0 = qb + (size_t)(tokbase + m) * DIM + kseg * 8;
    const ushort* q1 = qb + (size_t)(tokbase + 16 + m) * DIM + kseg * 8;
    #pragma unroll
    for (int kc = 0; kc < 4; ++kc) {
        bF0[kc] = *(const bf16x8*)(q0 + kc * 32);
        bF1[kc] = *(const bf16x8*)(q1 + kc * 32);
    }

    float R0[8], R1[8];
    #pragma unroll
    for (int i = 0; i < 8; ++i) { R0[i] = PACK_NEG_INF; R1[i] = PACK_NEG_INF; }

    const uint4* kb4 = (const uint4*)kbp;
    const int tbase = w * 32;   // this wave's first global 16-slot tile

    uint4 A[4], N[4];
    #pragma unroll
    for (int kc = 0; kc < 4; ++kc)
        A[kc] = kb4[(size_t)tbase * 256 + kc * 64 + lane];

    for (int t = 0; t < 32; ++t) {
        if (t < 31) {
            #pragma unroll
            for (int kc = 0; kc < 4; ++kc)
                N[kc] = kb4[(size_t)(tbase + t + 1) * 256 + kc * 64 + lane];
        }
        f32x4 acc0 = {0.f, 0.f, 0.f, 0.f};
        f32x4 acc1 = {0.f, 0.f, 0.f, 0.f};
        #pragma unroll
        for (int kc = 0; kc < 4; ++kc) {
            bf16x8 aF = *(const bf16x8*)&A[kc];
            acc0 = __builtin_amdgcn_mfma_f32_16x16x32_bf16(aF, bF0[kc], acc0, 0, 0, 0);
            acc1 = __builtin_amdgcn_mfma_f32_16x16x32_bf16(aF, bF1[kc], acc1, 0, 0, 0);
        }
        const int base = w * 512 + t * 16;
        float4 lrv = ((const float4*)lr)[(base >> 2) + kseg];
        unsigned invb = 4095u - (unsigned)(base + kseg * 4);
        ins_packed(R0, pack_score(acc0[0] + lrv.x, invb));
        ins_packed(R0, pack_score(acc0[1] + lrv.y, invb - 1));
        ins_packed(R0, pack_score(acc0[2] + lrv.z, invb - 2));
        ins_packed(R0, pack_score(acc0[3] + lrv.w, invb - 3));
        ins_packed(R1, pack_score(acc1[0] + lrv.x, invb));
        ins_packed(R1, pack_score(acc1[1] + lrv.y, invb - 1));
        ins_packed(R1, pack_score(acc1[2] + lrv.z, invb - 2));
        ins_packed(R1, pack_score(acc1[3] + lrv.w, invb - 3));
        #pragma unroll
        for (int kc = 0; kc < 4; ++kc) A[kc] = N[kc];
    }

    merge_out16(R0, kseg, &qS[m][w][0]);
    merge_out16(R1, kseg, &qS[m + 16][w][0]);
    __syncthreads();

    // 8-way merge of the eighths' sorted-desc lists -> exact global top-16
    if (tid < 32) {
        const int token = tokbase + tid;
        int p[8] = {0, 0, 0, 0, 0, 0, 0, 0};
        #pragma unroll
        for (int c = 0; c < 16; ++c) {
            float bv = -INFINITY; int bq = 0;
            #pragma unroll
            for (int j = 0; j < 8; ++j) {
                float v = (p[j] < 16) ? qS[tid][j][p[j]] : -INFINITY;
                if (v > bv) { bv = v; bq = j; }
            }
            cand[(size_t)token * 16 + c] = 4095 - (int)(__float_as_uint(bv) & 0xFFFu);
            ++p[bq];
        }
    }
}

// ---------------- kernel 2: fused fp32 rescue + softmax + V gather ----------
// (r3 proven: 59.4 us measured) 1 wave per token (4/block); lane = cand(16)
// x dim-quarter(4). Exact fp32 q.k on the 16-candidate pool; 16-wide bitonic
// (s desc, idx asc — same rank order as reference top_k); softmax on raw
// scores; wave gathers the 8 weighted fp16 V rows. Plain loads/stores (NT
// hints measured net-negative in r10: WRITE 66->77 MB). Floor analysis:
// 256 MB L2-requests on an 8 MB random-gather set vs 4 MB/XCD L2 -> ~54%
// hit -> ~118 MB past-L2 at ~2 TB/s miss service = the measured 59 us.
__device__ __forceinline__ float2 h2f2(unsigned u) {
    return __half22float2(*reinterpret_cast<const __half2*>(&u));
}
__launch_bounds__(256)
__global__ void rescue_gather_kernel(const float* __restrict__ query,
                                     const float* __restrict__ keys,
                                     const float* __restrict__ lr,
                                     const int*   __restrict__ cand,
                                     const ushort* __restrict__ vh,
                                     float* __restrict__ out,
                                     float* __restrict__ wout) {
    const int tid  = threadIdx.x;
    const int w    = tid >> 6;
    const int lane = tid & 63;
    const int token = blockIdx.x * 4 + w;
    const int c  = lane >> 2;    // candidate 0..15
    const int qp = lane & 3;     // dim quarter (32 floats)

    int ci = cand[(size_t)token * 16 + c];
    const float4* q4 = (const float4*)(query + (size_t)token * DIM) + qp * 8;
    const float4* k4 = (const float4*)(keys  + (size_t)ci    * DIM) + qp * 8;
    float sum = 0.f;
    #pragma unroll
    for (int i = 0; i < 8; ++i) {
        float4 a = q4[i], b = k4[i];
        sum = fmaf(a.x, b.x, sum); sum = fmaf(a.y, b.y, sum);
        sum = fmaf(a.z, b.z, sum); sum = fmaf(a.w, b.w, sum);
    }
    sum += __shfl_xor(sum, 1, 4);
    sum += __shfl_xor(sum, 2, 4);    // all 4 twins hold the full dot
    float raw = sum;
    float s   = sum + lr[ci];        // biased, exact fp32

    // bitonic sort of 16 candidates across lanes (twins mirror; partner lane
    // = lane ^ (j*4)). "mineFirst" = ranks before = (s desc, idx asc).
    #pragma unroll
    for (int k = 2; k <= 16; k <<= 1) {
        #pragma unroll
        for (int j = k >> 1; j >= 1; j >>= 1) {
            int off = j << 2;
            float s2 = __shfl_xor(s,   off, 64);
            float r2 = __shfl_xor(raw, off, 64);
            int   i2 = __shfl_xor(ci,  off, 64);
            bool mineFirst = (s > s2) || (s == s2 && ci < i2);
            bool lower = (c & j) == 0;
            bool asc   = (c & k) == 0;
            bool keep  = (lower == asc) ? mineFirst : !mineFirst;
            if (!keep) { s = s2; raw = r2; ci = i2; }
        }
    }
    // position c now holds rank c; broadcast top-8 (raw, idx) to all lanes
    float rsel[8]; int isel[8];
    #pragma unroll
    for (int r = 0; r < 8; ++r) {
        rsel[r] = __shfl(raw, r * 4, 64);
        isel[r] = __shfl(ci,  r * 4, 64);
    }

    // softmax on raw*SCALE — computed redundantly in every lane (weights
    // needed in registers for the gather)
    float mx = -INFINITY;
    #pragma unroll
    for (int k = 0; k < 8; ++k) { rsel[k] *= SCALE; mx = fmaxf(mx, rsel[k]); }
    float e[8]; float ssum = 0.f;
    #pragma unroll
    for (int k = 0; k < 8; ++k) { e[k] = expf(rsel[k] - mx); ssum += e[k]; }
    float inv = 1.0f / ssum;
    float wk[8];
    #pragma unroll
    for (int k = 0; k < 8; ++k) wk[k] = e[k] * inv;

    if (lane == 0) {
        #pragma unroll
        for (int k = 0; k < 8; ++k) wout[(size_t)token * 8 + k] = wk[k];
    }

    // fused gather: fp16 rows, 1024 halfs = 128 uint4; lane owns
    // dims [lane*8, lane*8+8) and [512+lane*8, 512+lane*8+8)
    float oA[8], oB[8];
    #pragma unroll
    for (int i = 0; i < 8; ++i) { oA[i] = 0.f; oB[i] = 0.f; }
    #pragma unroll
    for (int k = 0; k < 8; ++k) {
        const uint4* vr = (const uint4*)vh + (size_t)isel[k] * 128;
        float wkk = wk[k];
        uint4 va = vr[lane];
        uint4 vb = vr[lane + 64];
        float2 f;
        f = h2f2(va.x); oA[0] = fmaf(wkk, f.x, oA[0]); oA[1] = fmaf(wkk, f.y, oA[1]);
        f = h2f2(va.y); oA[2] = fmaf(wkk, f.x, oA[2]); oA[3] = fmaf(wkk, f.y, oA[3]);
        f = h2f2(va.z); oA[4] = fmaf(wkk, f.x, oA[4]); oA[5] = fmaf(wkk, f.y, oA[5]);
        f = h2f2(va.w); oA[6] = fmaf(wkk, f.x, oA[6]); oA[7] = fmaf(wkk, f.y, oA[7]);
        f = h2f2(vb.x); oB[0] = fmaf(wkk, f.x, oB[0]); oB[1] = fmaf(wkk, f.y, oB[1]);
        f = h2f2(vb.y); oB[2] = fmaf(wkk, f.x, oB[2]); oB[3] = fmaf(wkk, f.y, oB[3]);
        f = h2f2(vb.z); oB[4] = fmaf(wkk, f.x, oB[4]); oB[5] = fmaf(wkk, f.y, oB[5]);
        f = h2f2(vb.w); oB[6] = fmaf(wkk, f.x, oB[6]); oB[7] = fmaf(wkk, f.y, oB[7]);
    }
    float4* orow = (float4*)(out + (size_t)token * HDIM);
    orow[lane * 2]           = make_float4(oA[0], oA[1], oA[2], oA[3]);
    orow[lane * 2 + 1]       = make_float4(oA[4], oA[5], oA[6], oA[7]);
    orow[128 + lane * 2]     = make_float4(oB[0], oB[1], oB[2], oB[3]);
    orow[128 + lane * 2 + 1] = make_float4(oB[4], oB[5], oB[6], oB[7]);
}

// ---------------- launch ----------------
extern "C" void kernel_launch(void* const* d_in, const int* in_sizes, int n_in,
                              void* d_out, int out_size, void* d_ws, size_t ws_size,
                              hipStream_t stream) {
    const float* query  = (const float*)d_in[0];
    const float* keys   = (const float*)d_in[1];
    const float* values = (const float*)d_in[2];
    const float* rel    = (const float*)d_in[3];

    float* out  = (float*)d_out;                 // [16384, 1024]
    float* wout = out + (size_t)NTOK * HDIM;     // [16384, 8]

    char* ws = (char*)d_ws;
    float*  lr   = (float*)ws;   ws += 4096 * 4;                    // 16 KB
    ushort* qb   = (ushort*)ws;  ws += (size_t)NTOK * DIM * 2;      // 4 MB
    ushort* kbp  = (ushort*)ws;  ws += (size_t)NSLOTS * DIM * 2;    // 1 MB
    int*    cand = (int*)ws;     ws += (size_t)NTOK * 16 * 4;       // 1 MB
    ushort* vh   = (ushort*)ws;                                     // 8 MB fp16 V

    int prep_grid = (QB_N + KBP_N + LR_N + VH_N) / 256;   // = 4368
    hipLaunchKernelGGL(prep_kernel, dim3(prep_grid), dim3(256), 0, stream,
                       query, keys, rel, values, qb, kbp, lr, vh);
    hipLaunchKernelGGL(route_kernel, dim3(NTOK / 32), dim3(512), 0, stream,
                       qb, kbp, lr, cand);
    hipLaunchKernelGGL(rescue_gather_kernel, dim3(NTOK / 4), dim3(256), 0, stream,
                       query, keys, lr, cand, vh, out, wout);
}